// Round 13
// baseline (981.154 us; speedup 1.0000x reference)
//
#include <hip/hip_runtime.h>
#include <stdint.h>

#define NPTS 4096
#define KREG 1024
#define NS   64
#define NB   16
#define PTOT (NB*KREG*NS)        // 1048576 positions
#define NWAVE (PTOT/64)          // 16384
#define GATH_BLOCKS 256

typedef float v2f __attribute__((ext_vector_type(2)));
typedef __attribute__((ext_vector_type(8))) short bf16x8;
typedef __attribute__((ext_vector_type(4))) float f32x4;

// round-to-nearest-even f32 -> bf16 (bit trick; no NaN/Inf in data)
__device__ __forceinline__ unsigned short f2bf(float v) {
    unsigned u = __float_as_uint(v);
    u += 0x7FFFu + ((u >> 16) & 1u);
    return (unsigned short)(u >> 16);
}

#define DPPF(v, ctrl) __int_as_float(__builtin_amdgcn_mov_dpp( \
        __float_as_int(v), ctrl, 0xF, 0xF, true))

// ---------------------------------------------------------------------------
// FPS: 256 threads, 16 pts/thread, exact f32 (contract off), swizzled pcL,
// centroid stash in .w words. r12: per-thread argmax is a depth-4 pairwise
// TREE (first-index-wins preserved: lower-index operand first + strict >)
// instead of a serial 16-link cndmask chain -- cuts ~130cy of exposed
// dependency tail per iteration (1 wave/SIMD, no TLP to hide it).
// ---------------------------------------------------------------------------
__global__ __launch_bounds__(256) void fps_kernel(
    const float* __restrict__ pc, float* __restrict__ outC)
{
#pragma clang fp contract(off)
    __shared__ float4 pcL[NPTS];
    __shared__ alignas(16) unsigned long long wpart[2][4];

    const int b = blockIdx.x;
    const int t = threadIdx.x;
    const int wv = t >> 6;
    const int lane = t & 63;
    const float* px = pc + (size_t)b * 3 * NPTS;

    v2f lx[8], ly[8], lz[8], md[8];
    {
        const float4* px4 = (const float4*)(px + t * 16);
        const float4* py4 = (const float4*)(px + NPTS + t * 16);
        const float4* pz4 = (const float4*)(px + 2 * NPTS + t * 16);
        #pragma unroll
        for (int q = 0; q < 4; ++q) {
            float4 xx = px4[q], yy = py4[q], zz = pz4[q];
            lx[2*q]   = (v2f){xx.x, xx.y};  lx[2*q+1] = (v2f){xx.z, xx.w};
            ly[2*q]   = (v2f){yy.x, yy.y};  ly[2*q+1] = (v2f){yy.z, yy.w};
            lz[2*q]   = (v2f){zz.x, zz.y};  lz[2*q+1] = (v2f){zz.z, zz.w};
            md[2*q]   = (v2f){1e10f, 1e10f};
            md[2*q+1] = (v2f){1e10f, 1e10f};
            pcL[(4*q + 0) * 256 + t] = make_float4(xx.x, yy.x, zz.x, 0.f);
            pcL[(4*q + 1) * 256 + t] = make_float4(xx.y, yy.y, zz.y, 0.f);
            pcL[(4*q + 2) * 256 + t] = make_float4(xx.z, yy.z, zz.z, 0.f);
            pcL[(4*q + 3) * 256 + t] = make_float4(xx.w, yy.w, zz.w, 0.f);
        }
    }
    __syncthreads();
    float4 cc = pcL[0];

    for (int it = 0; it < KREG; ++it) {
        if (t == 0) {
            pcL[it].w        = cc.x;
            pcL[1024 + it].w = cc.y;
            pcL[2048 + it].w = cc.z;
        }
        const v2f cx2 = (v2f){cc.x, cc.x};
        const v2f cy2 = (v2f){cc.y, cc.y};
        const v2f cz2 = (v2f){cc.z, cc.z};
        float m[16];
        #pragma unroll
        for (int q = 0; q < 8; ++q) {
            v2f dx = lx[q] - cx2;
            v2f dy = ly[q] - cy2;
            v2f dz = lz[q] - cz2;
            v2f d  = (dx * dx + dy * dy) + dz * dz;
            v2f mm;
            mm.x = fminf(md[q].x, d.x);
            mm.y = fminf(md[q].y, d.y);
            md[q] = mm;
            m[2*q] = mm.x; m[2*q+1] = mm.y;
        }
        // depth-4 argmax tree; lower-index operand first + strict > on the
        // higher-index operand == exact first-index-wins (associative).
        float v8[8]; int j8[8];
        #pragma unroll
        for (int k = 0; k < 8; ++k) {
            bool g = m[2*k+1] > m[2*k];
            v8[k] = g ? m[2*k+1] : m[2*k];
            j8[k] = g ? 2*k+1 : 2*k;
        }
        float v4[4]; int j4[4];
        #pragma unroll
        for (int k = 0; k < 4; ++k) {
            bool g = v8[2*k+1] > v8[2*k];
            v4[k] = g ? v8[2*k+1] : v8[2*k];
            j4[k] = g ? j8[2*k+1] : j8[2*k];
        }
        float vv[2]; int jj[2];
        #pragma unroll
        for (int k = 0; k < 2; ++k) {
            bool g = v4[2*k+1] > v4[2*k];
            vv[k] = g ? v4[2*k+1] : v4[2*k];
            jj[k] = g ? j4[2*k+1] : j4[2*k];
        }
        bool gf = vv[1] > vv[0];
        float mbest = gf ? vv[1] : vv[0];
        int jbest = gf ? jj[1] : jj[0];

        float r = mbest;
        r = fmaxf(r, DPPF(r, 0xB1));
        r = fmaxf(r, DPPF(r, 0x4E));
        r = fmaxf(r, DPPF(r, 0x141));
        r = fmaxf(r, DPPF(r, 0x140));
        r = fmaxf(r, DPPF(r, 0x142));
        r = fmaxf(r, DPPF(r, 0x143));
        float mxw = __int_as_float(
            __builtin_amdgcn_readlane(__float_as_int(r), 63));
        unsigned long long ball = __ballot(mbest == mxw);
        int L = __ffsll((long long)ball) - 1;
        int jw = __builtin_amdgcn_readlane(jbest, L);
        unsigned pw = ((unsigned)(wv * 64 + L) << 4) + (unsigned)jw;
        unsigned long long key =
            ((unsigned long long)__float_as_uint(mxw) << 32) |
            (unsigned long long)(0xFFFFFFFFu - pw);
        if (lane == 0) wpart[it & 1][wv] = key;
        __syncthreads();
        const unsigned long long* wp = &wpart[it & 1][0];
        ulonglong2 k01 = *(const ulonglong2*)&wp[0];
        ulonglong2 k23 = *(const ulonglong2*)&wp[2];
        unsigned long long ka = (k01.x > k01.y) ? k01.x : k01.y;
        unsigned long long kb = (k23.x > k23.y) ? k23.x : k23.y;
        unsigned long long kk = (ka > kb) ? ka : kb;
        int f = (int)(0xFFFFFFFFu - (unsigned)kk);
        cc = pcL[(f & 15) * 256 + (f >> 4)];
    }
    __syncthreads();
    for (int i = t; i < KREG; i += 256) {
        outC[(size_t)b * 3 * KREG + i]            = pcL[i].w;
        outC[(size_t)b * 3 * KREG + KREG + i]     = pcL[1024 + i].w;
        outC[(size_t)b * 3 * KREG + 2 * KREG + i] = pcL[2048 + i].w;
    }
}

// ---------------------------------------------------------------------------
// Ball query r12: 4 centroids per WAVE (same-batch, consecutive k) -- each
// loaded point is tested against 4 centroids, cutting point loads and wave
// count 4x. Per-centroid logic (exact f32 formula, ballot/prefix writes,
// first-index pad) copied verbatim; writes self-disable once cnt>=NS, so
// gidx is bit-identical to the 1-centroid version.
// ---------------------------------------------------------------------------
__global__ __launch_bounds__(256) void ballquery_kernel(
    const float* __restrict__ pc, const float* __restrict__ outC,
    int* __restrict__ gidx)
{
    const int wv = threadIdx.x >> 6;
    const int lane = threadIdx.x & 63;
    const int gw0 = (blockIdx.x * 4 + wv) * 4;
    const int b = gw0 >> 10;
    const int k0 = gw0 & (KREG - 1);
    const float* px = pc + (size_t)b * 3 * NPTS;

    float cx[4], cy[4], cz[4], c2[4];
    int cnt[4] = {0, 0, 0, 0};
    int firstidx[4] = {-1, -1, -1, -1};
    #pragma unroll
    for (int c = 0; c < 4; ++c) {
        cx[c] = outC[(size_t)b * 3 * KREG + k0 + c];
        cy[c] = outC[(size_t)b * 3 * KREG + KREG + k0 + c];
        cz[c] = outC[(size_t)b * 3 * KREG + 2 * KREG + k0 + c];
        c2[c] = __fadd_rn(__fadd_rn(__fmul_rn(cx[c], cx[c]),
                                    __fmul_rn(cy[c], cy[c])),
                          __fmul_rn(cz[c], cz[c]));
    }
    const float r2 = 0.16f;

    for (int nb = 0; nb < NPTS / 64; ++nb) {
        int n = nb * 64 + lane;
        float x = px[n], y = px[NPTS + n], z = px[2 * NPTS + n];
        float x2 = __fadd_rn(__fadd_rn(__fmul_rn(x, x), __fmul_rn(y, y)),
                             __fmul_rn(z, z));
        #pragma unroll
        for (int c = 0; c < 4; ++c) {
            if (cnt[c] >= NS) continue;          // wave-uniform skip
            float dt = __fadd_rn(__fadd_rn(__fmul_rn(cx[c], x),
                                           __fmul_rn(cy[c], y)),
                                 __fmul_rn(cz[c], z));
            float sqd = __fsub_rn(__fadd_rn(c2[c], x2), __fmul_rn(2.0f, dt));
            bool pred = (sqd <= r2);
            unsigned long long mask = __ballot(pred);
            if (firstidx[c] < 0 && mask)
                firstidx[c] = nb * 64 + __ffsll((long long)mask) - 1;
            int pos = cnt[c] + __popcll(mask & ((1ull << lane) - 1ull));
            if (pred && pos < NS) gidx[(gw0 + c) * NS + pos] = n;
            cnt[c] += __popcll(mask);
        }
        if (cnt[0] >= NS && cnt[1] >= NS && cnt[2] >= NS && cnt[3] >= NS)
            break;
    }
    #pragma unroll
    for (int c = 0; c < 4; ++c)
        if (lane >= cnt[c]) gidx[(gw0 + c) * NS + lane] = firstidx[c];
}

// ---------------------------------------------------------------------------
// Gather (unchanged).
// ---------------------------------------------------------------------------
__global__ __launch_bounds__(256) void gather_kernel(
    const float* __restrict__ pc, const float* __restrict__ outC,
    const int* __restrict__ gidx, float* __restrict__ X0,
    float* __restrict__ mpart)
{
    float a[9] = {0, 0, 0, 0, 0, 0, 0, 0, 0};
    for (int p = blockIdx.x * 256 + threadIdx.x; p < PTOT; p += GATH_BLOCKS * 256) {
        int bk = p >> 6;
        int b = bk >> 10;
        int k = bk & (KREG - 1);
        int idx = gidx[p];
        const float* px = pc + (size_t)b * 3 * NPTS;
        float x = px[idx]            - outC[(size_t)b * 3 * KREG + k];
        float y = px[NPTS + idx]     - outC[(size_t)b * 3 * KREG + KREG + k];
        float z = px[2 * NPTS + idx] - outC[(size_t)b * 3 * KREG + 2 * KREG + k];
        X0[p] = x; X0[PTOT + p] = y; X0[2 * PTOT + p] = z;
        a[0] += x;     a[1] += y;     a[2] += z;
        a[3] += x * x; a[4] += y * y; a[5] += z * z;
        a[6] += x * y; a[7] += x * z; a[8] += y * z;
    }
    __shared__ float red[4][9];
    int wv = threadIdx.x >> 6;
    #pragma unroll
    for (int q = 0; q < 9; ++q) {
        float v = a[q];
        #pragma unroll
        for (int s = 32; s > 0; s >>= 1) v += __shfl_xor(v, s, 64);
        if ((threadIdx.x & 63) == 0) red[wv][q] = v;
    }
    __syncthreads();
    if (threadIdx.x < 9) {
        mpart[blockIdx.x * 9 + threadIdx.x] =
            red[0][threadIdx.x] + red[1][threadIdx.x] +
            red[2][threadIdx.x] + red[3][threadIdx.x];
    }
}

// ---------------------------------------------------------------------------
// BN1 finalize (unchanged).
// ---------------------------------------------------------------------------
__global__ void bn1_finalize(
    const float* __restrict__ mpart, const float* __restrict__ w1,
    const float* __restrict__ b1, const float* __restrict__ g1,
    const float* __restrict__ be1, float* __restrict__ sc1,
    float* __restrict__ sh1)
{
    __shared__ double M[9];
    int t = threadIdx.x;
    if (t < 9) {
        double s = 0;
        for (int i = 0; i < GATH_BLOCKS; ++i) s += (double)mpart[i * 9 + t];
        M[t] = s / (double)PTOT;
    }
    __syncthreads();
    if (t < 64) {
        double mux = M[0], muy = M[1], muz = M[2];
        double xx = M[3], yy = M[4], zz = M[5], xy = M[6], xz = M[7], yz = M[8];
        double wx = w1[t * 3], wy = w1[t * 3 + 1], wz = w1[t * 3 + 2], bb = b1[t];
        double wmu = wx * mux + wy * muy + wz * muz;
        double mean = wmu + bb;
        double ey2 = wx * wx * xx + wy * wy * yy + wz * wz * zz
                   + 2.0 * (wx * wy * xy + wx * wz * xz + wy * wz * yz)
                   + 2.0 * bb * wmu + bb * bb;
        double var = ey2 - mean * mean;
        double scale = (double)g1[t] / sqrt(var + 1e-5);
        sc1[t] = (float)scale;
        sh1[t] = (float)((double)be1[t] - mean * scale);
    }
}

// ---------------------------------------------------------------------------
// Prep: bf16 (RNE) conversion of w2 and w3, native [o][c] layout.
// ---------------------------------------------------------------------------
__global__ __launch_bounds__(256) void prep_kernel(
    const float* __restrict__ w2, const float* __restrict__ w3,
    unsigned short* __restrict__ w2h, unsigned short* __restrict__ w3h)
{
    int t = blockIdx.x * 256 + threadIdx.x;
    if (t < 4096) w2h[t] = f2bf(w2[t]);
    if (t < 8192) w3h[t] = f2bf(w3[t]);
}

// 2-MFMA plain-bf16 product over K=64 (two K=32 halves). Order FIXED; must be
// identical everywhere y2 is computed so BN2 stats are self-consistent.
#define MFMA_HI2(acc, ah0, bh0, ah1, bh1)                                      \
    acc = __builtin_amdgcn_mfma_f32_16x16x32_bf16(ah0, bh0, acc, 0, 0, 0);     \
    acc = __builtin_amdgcn_mfma_f32_16x16x32_bf16(ah1, bh1, acc, 0, 0, 0);

// ---------------------------------------------------------------------------
// Pass A: conv1 (vector) -> X1 bf16 LDS (16 KB) -> conv2 via bf16 MFMA ->
// per-channel sum/sumsq of y2 from C fragments (16-lane DPP reduce).
// ---------------------------------------------------------------------------
__global__ __launch_bounds__(256) void conv12_stats_kernel(
    const float* __restrict__ X0,
    const float* __restrict__ w1, const float* __restrict__ b1,
    const float* __restrict__ sc1, const float* __restrict__ sh1,
    const unsigned short* __restrict__ w2h, const float* __restrict__ b2,
    float* __restrict__ sum2, float* __restrict__ sq2)
{
    __shared__ alignas(16) unsigned short X1h[128 * 64];
    const int t = threadIdx.x;
    const int pos = t & 127;
    const int half = __builtin_amdgcn_readfirstlane(t >> 7);
    const int p = blockIdx.x * 128 + pos;

    float x = X0[p], y = X0[PTOT + p], z = X0[2 * PTOT + p];
    const int sw = (pos & 7) << 4;
    #pragma unroll
    for (int o2 = 0; o2 < 16; ++o2) {
        int oo = half * 32 + o2 * 2;
        float v0 = b1[oo];
        v0 = fmaf(w1[oo * 3 + 2], z, v0);
        v0 = fmaf(w1[oo * 3 + 1], y, v0);
        v0 = fmaf(w1[oo * 3 + 0], x, v0);
        v0 = fmaxf(fmaf(v0, sc1[oo], sh1[oo]), 0.f);
        float v1 = b1[oo + 1];
        v1 = fmaf(w1[oo * 3 + 5], z, v1);
        v1 = fmaf(w1[oo * 3 + 4], y, v1);
        v1 = fmaf(w1[oo * 3 + 3], x, v1);
        v1 = fmaxf(fmaf(v1, sc1[oo + 1], sh1[oo + 1]), 0.f);
        unsigned short h0 = f2bf(v0), h1 = f2bf(v1);
        int boff = pos * 128 + ((oo * 2) ^ sw);
        *(unsigned*)((char*)X1h + boff) = (unsigned)h0 | ((unsigned)h1 << 16);
    }
    __syncthreads();

    const int wv2 = __builtin_amdgcn_readfirstlane(t >> 6);
    const int lcol = t & 15;
    const int lk = (t & 63) >> 4;

    bf16x8 ah[2];
    #pragma unroll
    for (int kh = 0; kh < 2; ++kh) {
        int idx = (wv2 * 16 + lcol) * 64 + kh * 32 + lk * 8;
        ah[kh] = *(const bf16x8*)(w2h + idx);
    }
    f32x4 b2v = *(const f32x4*)&b2[wv2 * 16 + lk * 4];

    float ssm[2][4] = {{0}}, ssq[2][4] = {{0}};
    #pragma unroll
    for (int nt = 0; nt < 8; ++nt) {
        const int g = nt >> 2;
        int prow = nt * 16 + lcol;
        int rb = prow * 128;
        int psw = (prow & 7) << 4;
        bf16x8 bh[2];
        #pragma unroll
        for (int kh = 0; kh < 2; ++kh) {
            int off = rb + ((kh * 64 + lk * 16) ^ psw);
            bh[kh] = *(const bf16x8*)((const char*)X1h + off);
        }
        f32x4 acc = {0.f, 0.f, 0.f, 0.f};
        MFMA_HI2(acc, ah[0], bh[0], ah[1], bh[1])
        #pragma unroll
        for (int r = 0; r < 4; ++r) {
            float v = acc[r] + b2v[r];
            ssm[g][r] += v;
            ssq[g][r] = fmaf(v, v, ssq[g][r]);
        }
    }
    #pragma unroll
    for (int g = 0; g < 2; ++g) {
        #pragma unroll
        for (int r = 0; r < 4; ++r) {
            float s = ssm[g][r];
            s += DPPF(s, 0xB1);  s += DPPF(s, 0x4E);
            s += DPPF(s, 0x141); s += DPPF(s, 0x140);
            float q = ssq[g][r];
            q += DPPF(q, 0xB1);  q += DPPF(q, 0x4E);
            q += DPPF(q, 0x141); q += DPPF(q, 0x140);
            if (lcol == 0) {
                int o = wv2 * 16 + lk * 4 + r;
                size_t gw = (size_t)(blockIdx.x * 2 + g);
                sum2[(size_t)o * NWAVE + gw] = s;
                sq2[(size_t)o * NWAVE + gw] = q;
            }
        }
    }
}

// ---------------------------------------------------------------------------
// BN finalize (unchanged).
// ---------------------------------------------------------------------------
__global__ __launch_bounds__(256) void bn_finalize_kernel(
    const float* __restrict__ sumb, const float* __restrict__ sqb,
    const float* __restrict__ g, const float* __restrict__ be,
    float* __restrict__ sc, float* __restrict__ sh)
{
    int o = blockIdx.x, t = threadIdx.x;
    double s = 0, q = 0;
    for (int i = t; i < NWAVE; i += 256) {
        s += (double)sumb[(size_t)o * NWAVE + i];
        q += (double)sqb[(size_t)o * NWAVE + i];
    }
    #pragma unroll
    for (int m = 32; m > 0; m >>= 1) {
        s += __shfl_xor(s, m, 64);
        q += __shfl_xor(q, m, 64);
    }
    __shared__ double rs[4], rq[4];
    if ((t & 63) == 0) { rs[t >> 6] = s; rq[t >> 6] = q; }
    __syncthreads();
    if (t == 0) {
        s = rs[0] + rs[1] + rs[2] + rs[3];
        q = rq[0] + rq[1] + rq[2] + rq[3];
        double mean = s / (double)PTOT;
        double var = q / (double)PTOT - mean * mean;
        double scale = (double)g[o] / sqrt(var + 1e-5);
        sc[o] = (float)scale;
        sh[o] = (float)((double)be[o] - mean * scale);
    }
}

// ---------------------------------------------------------------------------
// Pass B: conv1 vector -> X1 bf16 LDS -> conv2 MFMA (identical sequence to
// Pass A) -> BN2+ReLU -> X2 bf16 LDS -> conv3 MFMA -> per-(bk,o) max/min +
// sum/sq from fragments. LDS 32 KB -> ~4 blocks/CU.
// ---------------------------------------------------------------------------
__global__ __launch_bounds__(256) void conv123_kernel(
    const float* __restrict__ X0,
    const float* __restrict__ w1, const float* __restrict__ b1,
    const float* __restrict__ sc1, const float* __restrict__ sh1,
    const unsigned short* __restrict__ w2h, const float* __restrict__ b2,
    const float* __restrict__ sc2, const float* __restrict__ sh2,
    const unsigned short* __restrict__ w3h, const float* __restrict__ b3,
    float* __restrict__ y3max, float* __restrict__ y3min,
    float* __restrict__ sum3, float* __restrict__ sq3)
{
    __shared__ alignas(16) unsigned short X1h[128 * 64];
    __shared__ alignas(16) unsigned short X2h[128 * 64];
    __shared__ alignas(16) float b3L[128];

    const int t = threadIdx.x;
    const int pos = t & 127;
    const int half = __builtin_amdgcn_readfirstlane(t >> 7);
    const int p = blockIdx.x * 128 + pos;
    if (t < 128) b3L[t] = b3[t];

    float x = X0[p], y = X0[PTOT + p], z = X0[2 * PTOT + p];
    const int sw = (pos & 7) << 4;
    #pragma unroll
    for (int o2 = 0; o2 < 16; ++o2) {
        int oo = half * 32 + o2 * 2;
        float v0 = b1[oo];
        v0 = fmaf(w1[oo * 3 + 2], z, v0);
        v0 = fmaf(w1[oo * 3 + 1], y, v0);
        v0 = fmaf(w1[oo * 3 + 0], x, v0);
        v0 = fmaxf(fmaf(v0, sc1[oo], sh1[oo]), 0.f);
        float v1 = b1[oo + 1];
        v1 = fmaf(w1[oo * 3 + 5], z, v1);
        v1 = fmaf(w1[oo * 3 + 4], y, v1);
        v1 = fmaf(w1[oo * 3 + 3], x, v1);
        v1 = fmaxf(fmaf(v1, sc1[oo + 1], sh1[oo + 1]), 0.f);
        unsigned short h0 = f2bf(v0), h1 = f2bf(v1);
        int boff = pos * 128 + ((oo * 2) ^ sw);
        *(unsigned*)((char*)X1h + boff) = (unsigned)h0 | ((unsigned)h1 << 16);
    }
    __syncthreads();

    const int wv2 = __builtin_amdgcn_readfirstlane(t >> 6);
    const int lcol = t & 15;
    const int lk = (t & 63) >> 4;

    // conv2 via MFMA (identical math to Pass A) -> BN2+ReLU -> X2
    {
        bf16x8 ah[2];
        #pragma unroll
        for (int kh = 0; kh < 2; ++kh) {
            int idx = (wv2 * 16 + lcol) * 64 + kh * 32 + lk * 8;
            ah[kh] = *(const bf16x8*)(w2h + idx);
        }
        f32x4 b2v = *(const f32x4*)&b2[wv2 * 16 + lk * 4];
        f32x4 sc2v = *(const f32x4*)&sc2[wv2 * 16 + lk * 4];
        f32x4 sh2v = *(const f32x4*)&sh2[wv2 * 16 + lk * 4];
        const int ch0 = wv2 * 16 + lk * 4;

        #pragma unroll
        for (int nt = 0; nt < 8; ++nt) {
            int prow = nt * 16 + lcol;
            int rb = prow * 128;
            int psw = (prow & 7) << 4;
            bf16x8 bh[2];
            #pragma unroll
            for (int kh = 0; kh < 2; ++kh) {
                int off = rb + ((kh * 64 + lk * 16) ^ psw);
                bh[kh] = *(const bf16x8*)((const char*)X1h + off);
            }
            f32x4 acc = {0.f, 0.f, 0.f, 0.f};
            MFMA_HI2(acc, ah[0], bh[0], ah[1], bh[1])
            unsigned short hh[4];
            #pragma unroll
            for (int r = 0; r < 4; ++r) {
                float v = acc[r] + b2v[r];
                float x2 = fmaxf(fmaf(v, sc2v[r], sh2v[r]), 0.f);
                hh[r] = f2bf(x2);
            }
            int b0 = prow * 128 + ((ch0 * 2) ^ psw);
            *(unsigned*)((char*)X2h + b0)     = (unsigned)hh[0] | ((unsigned)hh[1] << 16);
            *(unsigned*)((char*)X2h + b0 + 4) = (unsigned)hh[2] | ((unsigned)hh[3] << 16);
        }
    }
    __syncthreads();

    // conv3 via MFMA (2 m-tiles/wave over 128 channels)
    bf16x8 ah3[2][2];
    f32x4 bias[2];
    #pragma unroll
    for (int mt = 0; mt < 2; ++mt) {
        #pragma unroll
        for (int kh = 0; kh < 2; ++kh) {
            int m = (wv2 * 2 + mt) * 16 + lcol;
            int idx = m * 64 + kh * 32 + lk * 8;
            ah3[mt][kh] = *(const bf16x8*)(w3h + idx);
        }
        bias[mt] = *(const f32x4*)&b3L[(wv2 * 2 + mt) * 16 + lk * 4];
    }

    float smx[2][2][4], smn[2][2][4], ssm[2][2][4], ssq[2][2][4];
    #pragma unroll
    for (int g = 0; g < 2; ++g)
        #pragma unroll
        for (int mt = 0; mt < 2; ++mt)
            #pragma unroll
            for (int r = 0; r < 4; ++r) {
                smx[g][mt][r] = -1e30f; smn[g][mt][r] = 1e30f;
                ssm[g][mt][r] = 0.f;    ssq[g][mt][r] = 0.f;
            }

    #pragma unroll
    for (int nt = 0; nt < 8; ++nt) {
        const int g = nt >> 2;
        int prow = nt * 16 + lcol;
        int rb = prow * 128;
        int psw = (prow & 7) << 4;
        bf16x8 bh[2];
        #pragma unroll
        for (int kh = 0; kh < 2; ++kh) {
            int off = rb + ((kh * 64 + lk * 16) ^ psw);
            bh[kh] = *(const bf16x8*)((const char*)X2h + off);
        }
        #pragma unroll
        for (int mt = 0; mt < 2; ++mt) {
            f32x4 acc = {0.f, 0.f, 0.f, 0.f};
            MFMA_HI2(acc, ah3[mt][0], bh[0], ah3[mt][1], bh[1])
            #pragma unroll
            for (int r = 0; r < 4; ++r) {
                float v = acc[r] + bias[mt][r];
                smx[g][mt][r] = fmaxf(smx[g][mt][r], v);
                smn[g][mt][r] = fminf(smn[g][mt][r], v);
                ssm[g][mt][r] += v;
                ssq[g][mt][r] = fmaf(v, v, ssq[g][mt][r]);
            }
        }
    }

    #pragma unroll
    for (int g = 0; g < 2; ++g) {
        #pragma unroll
        for (int mt = 0; mt < 2; ++mt) {
            #pragma unroll
            for (int r = 0; r < 4; ++r) {
                float a = smx[g][mt][r];
                a = fmaxf(a, DPPF(a, 0xB1));  a = fmaxf(a, DPPF(a, 0x4E));
                a = fmaxf(a, DPPF(a, 0x141)); a = fmaxf(a, DPPF(a, 0x140));
                float c = smn[g][mt][r];
                c = fminf(c, DPPF(c, 0xB1));  c = fminf(c, DPPF(c, 0x4E));
                c = fminf(c, DPPF(c, 0x141)); c = fminf(c, DPPF(c, 0x140));
                float s = ssm[g][mt][r];
                s += DPPF(s, 0xB1);  s += DPPF(s, 0x4E);
                s += DPPF(s, 0x141); s += DPPF(s, 0x140);
                float q = ssq[g][mt][r];
                q += DPPF(q, 0xB1);  q += DPPF(q, 0x4E);
                q += DPPF(q, 0x141); q += DPPF(q, 0x140);
                if (lcol == 0) {
                    int o = (wv2 * 2 + mt) * 16 + lk * 4 + r;
                    size_t gw = (size_t)(blockIdx.x * 2 + g);
                    y3max[gw * 128 + o] = a;
                    y3min[gw * 128 + o] = c;
                    sum3[(size_t)o * NWAVE + gw] = s;
                    sq3[(size_t)o * NWAVE + gw] = q;
                }
            }
        }
    }
}

// ---------------------------------------------------------------------------
// Final feats (unchanged).
// ---------------------------------------------------------------------------
__global__ __launch_bounds__(256) void feats_kernel(
    const float* __restrict__ y3max, const float* __restrict__ y3min,
    const float* __restrict__ sc3, const float* __restrict__ sh3,
    float* __restrict__ feats)
{
    __shared__ float tile[64][129];
    int blk = blockIdx.x;
    int b = blk >> 4, kt = blk & 15;
    int t = threadIdx.x;
    size_t bk0 = (size_t)(b * KREG + kt * 64);
    #pragma unroll
    for (int i = 0; i < 32; ++i) {
        int idx = i * 256 + t;
        int o = idx & 127, kk = idx >> 7;
        float a = sc3[o];
        float v = (a >= 0.f) ? y3max[(bk0 + kk) * 128 + o]
                             : y3min[(bk0 + kk) * 128 + o];
        tile[kk][o] = fmaxf(fmaf(v, a, sh3[o]), 0.0f);
    }
    __syncthreads();
    #pragma unroll
    for (int i = 0; i < 32; ++i) {
        int idx = i * 256 + t;
        int kk = idx & 63, o = idx >> 6;
        feats[(size_t)b * 128 * KREG + (size_t)o * KREG + kt * 64 + kk] = tile[kk][o];
    }
}

// ---------------------------------------------------------------------------
extern "C" void kernel_launch(void* const* d_in, const int* in_sizes, int n_in,
                              void* d_out, int out_size, void* d_ws, size_t ws_size,
                              hipStream_t stream)
{
    const float* pc  = (const float*)d_in[0];
    const float* w1  = (const float*)d_in[1];
    const float* b1  = (const float*)d_in[2];
    const float* g1  = (const float*)d_in[3];
    const float* be1 = (const float*)d_in[4];
    const float* w2  = (const float*)d_in[5];
    const float* b2  = (const float*)d_in[6];
    const float* g2  = (const float*)d_in[7];
    const float* be2 = (const float*)d_in[8];
    const float* w3  = (const float*)d_in[9];
    const float* b3  = (const float*)d_in[10];
    const float* g3  = (const float*)d_in[11];
    const float* be3 = (const float*)d_in[12];

    float* outC  = (float*)d_out;                      // (16,3,1024)
    float* feats = (float*)d_out + NB * 3 * KREG;      // (16,128,1024)

    const size_t MB = 1024 * 1024;
    char* ws = (char*)d_ws;
    int*   gidx  = (int*)ws;                           // 4 MB
    float* X0    = (float*)(ws + 4 * MB);              // 12 MB (3 x P)
    float* mpart = (float*)(ws + 16 * MB);             // 9216 B
    float* sc1   = (float*)(ws + 16 * MB + 16 * 1024);
    float* sh1   = (float*)(ws + 16 * MB + 17 * 1024);
    float* sc2   = (float*)(ws + 16 * MB + 18 * 1024);
    float* sh2   = (float*)(ws + 16 * MB + 19 * 1024);
    float* sc3   = (float*)(ws + 16 * MB + 20 * 1024);
    float* sh3   = (float*)(ws + 16 * MB + 21 * 1024);
    unsigned short* w2h = (unsigned short*)(ws + 16 * MB + 32 * 1024);  // 8 KB
    unsigned short* w3h = (unsigned short*)(ws + 16 * MB + 64 * 1024);  // 16 KB
    float* sum2  = (float*)(ws + 17 * MB);             // 4 MB
    float* sq2   = (float*)(ws + 21 * MB);             // 4 MB
    float* sum3  = (float*)(ws + 25 * MB);             // 8 MB
    float* sq3   = (float*)(ws + 33 * MB);             // 8 MB
    float* y3max = (float*)(ws + 41 * MB);             // 8 MB
    float* y3min = (float*)(ws + 49 * MB);             // 8 MB

    fps_kernel<<<NB, 256, 0, stream>>>(pc, outC);
    ballquery_kernel<<<(NB * KREG) / 16, 256, 0, stream>>>(pc, outC, gidx);
    gather_kernel<<<GATH_BLOCKS, 256, 0, stream>>>(pc, outC, gidx, X0, mpart);
    bn1_finalize<<<1, 64, 0, stream>>>(mpart, w1, b1, g1, be1, sc1, sh1);
    prep_kernel<<<32, 256, 0, stream>>>(w2, w3, w2h, w3h);
    conv12_stats_kernel<<<PTOT / 128, 256, 0, stream>>>(
        X0, w1, b1, sc1, sh1, w2h, b2, sum2, sq2);
    bn_finalize_kernel<<<64, 256, 0, stream>>>(sum2, sq2, g2, be2, sc2, sh2);
    conv123_kernel<<<PTOT / 128, 256, 0, stream>>>(
        X0, w1, b1, sc1, sh1, w2h, b2, sc2, sh2, w3h, b3,
        y3max, y3min, sum3, sq3);
    bn_finalize_kernel<<<128, 256, 0, stream>>>(sum3, sq3, g3, be3, sc3, sh3);
    feats_kernel<<<NB * (KREG / 64), 256, 0, stream>>>(y3max, y3min, sc3, sh3, feats);
}

// Round 14
// 828.135 us; speedup vs baseline: 1.1848x; 1.1848x over previous
//
#include <hip/hip_runtime.h>
#include <stdint.h>

#define NPTS 4096
#define KREG 1024
#define NS   64
#define NB   16
#define PTOT (NB*KREG*NS)        // 1048576 positions
#define NWAVE (PTOT/64)          // 16384
#define GATH_BLOCKS 256

typedef float v2f __attribute__((ext_vector_type(2)));
typedef __attribute__((ext_vector_type(8))) short bf16x8;
typedef __attribute__((ext_vector_type(4))) float f32x4;

// round-to-nearest-even f32 -> bf16 (bit trick; no NaN/Inf in data)
__device__ __forceinline__ unsigned short f2bf(float v) {
    unsigned u = __float_as_uint(v);
    u += 0x7FFFu + ((u >> 16) & 1u);
    return (unsigned short)(u >> 16);
}

#define DPPF(v, ctrl) __int_as_float(__builtin_amdgcn_mov_dpp( \
        __float_as_int(v), ctrl, 0xF, 0xF, true))

// ---------------------------------------------------------------------------
// FPS (r11 version, restored): 256 threads, 16 pts/thread, exact f32
// (contract off), SERIAL argmax chain (pipelines under the distance
// computation -- r12's tree variant regressed 598->757us), DPP reduce,
// swizzled pcL, centroid stash in .w words.
// ---------------------------------------------------------------------------
__global__ __launch_bounds__(256) void fps_kernel(
    const float* __restrict__ pc, float* __restrict__ outC)
{
#pragma clang fp contract(off)
    __shared__ float4 pcL[NPTS];
    __shared__ alignas(16) unsigned long long wpart[2][4];

    const int b = blockIdx.x;
    const int t = threadIdx.x;
    const int wv = t >> 6;
    const int lane = t & 63;
    const float* px = pc + (size_t)b * 3 * NPTS;

    v2f lx[8], ly[8], lz[8], md[8];
    {
        const float4* px4 = (const float4*)(px + t * 16);
        const float4* py4 = (const float4*)(px + NPTS + t * 16);
        const float4* pz4 = (const float4*)(px + 2 * NPTS + t * 16);
        #pragma unroll
        for (int q = 0; q < 4; ++q) {
            float4 xx = px4[q], yy = py4[q], zz = pz4[q];
            lx[2*q]   = (v2f){xx.x, xx.y};  lx[2*q+1] = (v2f){xx.z, xx.w};
            ly[2*q]   = (v2f){yy.x, yy.y};  ly[2*q+1] = (v2f){yy.z, yy.w};
            lz[2*q]   = (v2f){zz.x, zz.y};  lz[2*q+1] = (v2f){zz.z, zz.w};
            md[2*q]   = (v2f){1e10f, 1e10f};
            md[2*q+1] = (v2f){1e10f, 1e10f};
            pcL[(4*q + 0) * 256 + t] = make_float4(xx.x, yy.x, zz.x, 0.f);
            pcL[(4*q + 1) * 256 + t] = make_float4(xx.y, yy.y, zz.y, 0.f);
            pcL[(4*q + 2) * 256 + t] = make_float4(xx.z, yy.z, zz.z, 0.f);
            pcL[(4*q + 3) * 256 + t] = make_float4(xx.w, yy.w, zz.w, 0.f);
        }
    }
    __syncthreads();
    float4 cc = pcL[0];

    for (int it = 0; it < KREG; ++it) {
        if (t == 0) {
            pcL[it].w        = cc.x;
            pcL[1024 + it].w = cc.y;
            pcL[2048 + it].w = cc.z;
        }
        const v2f cx2 = (v2f){cc.x, cc.x};
        const v2f cy2 = (v2f){cc.y, cc.y};
        const v2f cz2 = (v2f){cc.z, cc.z};
        float mbest = -1.0f;
        int jbest = 0;
        #pragma unroll
        for (int q = 0; q < 8; ++q) {
            v2f dx = lx[q] - cx2;
            v2f dy = ly[q] - cy2;
            v2f dz = lz[q] - cz2;
            v2f d  = (dx * dx + dy * dy) + dz * dz;
            v2f m;
            m.x = fminf(md[q].x, d.x);
            m.y = fminf(md[q].y, d.y);
            md[q] = m;
            if (m.x > mbest) { mbest = m.x; jbest = 2 * q; }
            if (m.y > mbest) { mbest = m.y; jbest = 2 * q + 1; }
        }
        float r = mbest;
        r = fmaxf(r, DPPF(r, 0xB1));
        r = fmaxf(r, DPPF(r, 0x4E));
        r = fmaxf(r, DPPF(r, 0x141));
        r = fmaxf(r, DPPF(r, 0x140));
        r = fmaxf(r, DPPF(r, 0x142));
        r = fmaxf(r, DPPF(r, 0x143));
        float mxw = __int_as_float(
            __builtin_amdgcn_readlane(__float_as_int(r), 63));
        unsigned long long ball = __ballot(mbest == mxw);
        int L = __ffsll((long long)ball) - 1;
        int jw = __builtin_amdgcn_readlane(jbest, L);
        unsigned pw = ((unsigned)(wv * 64 + L) << 4) + (unsigned)jw;
        unsigned long long key =
            ((unsigned long long)__float_as_uint(mxw) << 32) |
            (unsigned long long)(0xFFFFFFFFu - pw);
        if (lane == 0) wpart[it & 1][wv] = key;
        __syncthreads();
        const unsigned long long* wp = &wpart[it & 1][0];
        ulonglong2 k01 = *(const ulonglong2*)&wp[0];
        ulonglong2 k23 = *(const ulonglong2*)&wp[2];
        unsigned long long ka = (k01.x > k01.y) ? k01.x : k01.y;
        unsigned long long kb = (k23.x > k23.y) ? k23.x : k23.y;
        unsigned long long kk = (ka > kb) ? ka : kb;
        int f = (int)(0xFFFFFFFFu - (unsigned)kk);
        cc = pcL[(f & 15) * 256 + (f >> 4)];
    }
    __syncthreads();
    for (int i = t; i < KREG; i += 256) {
        outC[(size_t)b * 3 * KREG + i]            = pcL[i].w;
        outC[(size_t)b * 3 * KREG + KREG + i]     = pcL[1024 + i].w;
        outC[(size_t)b * 3 * KREG + 2 * KREG + i] = pcL[2048 + i].w;
    }
}

// ---------------------------------------------------------------------------
// Ball query (r12 version, kept): 4 centroids per WAVE -- each loaded point
// tested against 4 centroids; per-centroid logic verbatim, gidx bit-identical.
// ---------------------------------------------------------------------------
__global__ __launch_bounds__(256) void ballquery_kernel(
    const float* __restrict__ pc, const float* __restrict__ outC,
    int* __restrict__ gidx)
{
    const int wv = threadIdx.x >> 6;
    const int lane = threadIdx.x & 63;
    const int gw0 = (blockIdx.x * 4 + wv) * 4;
    const int b = gw0 >> 10;
    const int k0 = gw0 & (KREG - 1);
    const float* px = pc + (size_t)b * 3 * NPTS;

    float cx[4], cy[4], cz[4], c2[4];
    int cnt[4] = {0, 0, 0, 0};
    int firstidx[4] = {-1, -1, -1, -1};
    #pragma unroll
    for (int c = 0; c < 4; ++c) {
        cx[c] = outC[(size_t)b * 3 * KREG + k0 + c];
        cy[c] = outC[(size_t)b * 3 * KREG + KREG + k0 + c];
        cz[c] = outC[(size_t)b * 3 * KREG + 2 * KREG + k0 + c];
        c2[c] = __fadd_rn(__fadd_rn(__fmul_rn(cx[c], cx[c]),
                                    __fmul_rn(cy[c], cy[c])),
                          __fmul_rn(cz[c], cz[c]));
    }
    const float r2 = 0.16f;

    for (int nb = 0; nb < NPTS / 64; ++nb) {
        int n = nb * 64 + lane;
        float x = px[n], y = px[NPTS + n], z = px[2 * NPTS + n];
        float x2 = __fadd_rn(__fadd_rn(__fmul_rn(x, x), __fmul_rn(y, y)),
                             __fmul_rn(z, z));
        #pragma unroll
        for (int c = 0; c < 4; ++c) {
            if (cnt[c] >= NS) continue;          // wave-uniform skip
            float dt = __fadd_rn(__fadd_rn(__fmul_rn(cx[c], x),
                                           __fmul_rn(cy[c], y)),
                                 __fmul_rn(cz[c], z));
            float sqd = __fsub_rn(__fadd_rn(c2[c], x2), __fmul_rn(2.0f, dt));
            bool pred = (sqd <= r2);
            unsigned long long mask = __ballot(pred);
            if (firstidx[c] < 0 && mask)
                firstidx[c] = nb * 64 + __ffsll((long long)mask) - 1;
            int pos = cnt[c] + __popcll(mask & ((1ull << lane) - 1ull));
            if (pred && pos < NS) gidx[(gw0 + c) * NS + pos] = n;
            cnt[c] += __popcll(mask);
        }
        if (cnt[0] >= NS && cnt[1] >= NS && cnt[2] >= NS && cnt[3] >= NS)
            break;
    }
    #pragma unroll
    for (int c = 0; c < 4; ++c)
        if (lane >= cnt[c]) gidx[(gw0 + c) * NS + lane] = firstidx[c];
}

// ---------------------------------------------------------------------------
// Gather (unchanged).
// ---------------------------------------------------------------------------
__global__ __launch_bounds__(256) void gather_kernel(
    const float* __restrict__ pc, const float* __restrict__ outC,
    const int* __restrict__ gidx, float* __restrict__ X0,
    float* __restrict__ mpart)
{
    float a[9] = {0, 0, 0, 0, 0, 0, 0, 0, 0};
    for (int p = blockIdx.x * 256 + threadIdx.x; p < PTOT; p += GATH_BLOCKS * 256) {
        int bk = p >> 6;
        int b = bk >> 10;
        int k = bk & (KREG - 1);
        int idx = gidx[p];
        const float* px = pc + (size_t)b * 3 * NPTS;
        float x = px[idx]            - outC[(size_t)b * 3 * KREG + k];
        float y = px[NPTS + idx]     - outC[(size_t)b * 3 * KREG + KREG + k];
        float z = px[2 * NPTS + idx] - outC[(size_t)b * 3 * KREG + 2 * KREG + k];
        X0[p] = x; X0[PTOT + p] = y; X0[2 * PTOT + p] = z;
        a[0] += x;     a[1] += y;     a[2] += z;
        a[3] += x * x; a[4] += y * y; a[5] += z * z;
        a[6] += x * y; a[7] += x * z; a[8] += y * z;
    }
    __shared__ float red[4][9];
    int wv = threadIdx.x >> 6;
    #pragma unroll
    for (int q = 0; q < 9; ++q) {
        float v = a[q];
        #pragma unroll
        for (int s = 32; s > 0; s >>= 1) v += __shfl_xor(v, s, 64);
        if ((threadIdx.x & 63) == 0) red[wv][q] = v;
    }
    __syncthreads();
    if (threadIdx.x < 9) {
        mpart[blockIdx.x * 9 + threadIdx.x] =
            red[0][threadIdx.x] + red[1][threadIdx.x] +
            red[2][threadIdx.x] + red[3][threadIdx.x];
    }
}

// ---------------------------------------------------------------------------
// BN1 finalize (unchanged).
// ---------------------------------------------------------------------------
__global__ void bn1_finalize(
    const float* __restrict__ mpart, const float* __restrict__ w1,
    const float* __restrict__ b1, const float* __restrict__ g1,
    const float* __restrict__ be1, float* __restrict__ sc1,
    float* __restrict__ sh1)
{
    __shared__ double M[9];
    int t = threadIdx.x;
    if (t < 9) {
        double s = 0;
        for (int i = 0; i < GATH_BLOCKS; ++i) s += (double)mpart[i * 9 + t];
        M[t] = s / (double)PTOT;
    }
    __syncthreads();
    if (t < 64) {
        double mux = M[0], muy = M[1], muz = M[2];
        double xx = M[3], yy = M[4], zz = M[5], xy = M[6], xz = M[7], yz = M[8];
        double wx = w1[t * 3], wy = w1[t * 3 + 1], wz = w1[t * 3 + 2], bb = b1[t];
        double wmu = wx * mux + wy * muy + wz * muz;
        double mean = wmu + bb;
        double ey2 = wx * wx * xx + wy * wy * yy + wz * wz * zz
                   + 2.0 * (wx * wy * xy + wx * wz * xz + wy * wz * yz)
                   + 2.0 * bb * wmu + bb * bb;
        double var = ey2 - mean * mean;
        double scale = (double)g1[t] / sqrt(var + 1e-5);
        sc1[t] = (float)scale;
        sh1[t] = (float)((double)be1[t] - mean * scale);
    }
}

// ---------------------------------------------------------------------------
// Prep: bf16 (RNE) conversion of w2 and w3, native [o][c] layout.
// ---------------------------------------------------------------------------
__global__ __launch_bounds__(256) void prep_kernel(
    const float* __restrict__ w2, const float* __restrict__ w3,
    unsigned short* __restrict__ w2h, unsigned short* __restrict__ w3h)
{
    int t = blockIdx.x * 256 + threadIdx.x;
    if (t < 4096) w2h[t] = f2bf(w2[t]);
    if (t < 8192) w3h[t] = f2bf(w3[t]);
}

// 2-MFMA plain-bf16 product over K=64 (two K=32 halves). Order FIXED; must be
// identical everywhere y2 is computed so BN2 stats are self-consistent.
#define MFMA_HI2(acc, ah0, bh0, ah1, bh1)                                      \
    acc = __builtin_amdgcn_mfma_f32_16x16x32_bf16(ah0, bh0, acc, 0, 0, 0);     \
    acc = __builtin_amdgcn_mfma_f32_16x16x32_bf16(ah1, bh1, acc, 0, 0, 0);

// ---------------------------------------------------------------------------
// Pass A: conv1 (vector) -> X1 bf16 LDS (16 KB) -> conv2 via bf16 MFMA ->
// per-channel sum/sumsq of y2 from C fragments (16-lane DPP reduce).
// ---------------------------------------------------------------------------
__global__ __launch_bounds__(256) void conv12_stats_kernel(
    const float* __restrict__ X0,
    const float* __restrict__ w1, const float* __restrict__ b1,
    const float* __restrict__ sc1, const float* __restrict__ sh1,
    const unsigned short* __restrict__ w2h, const float* __restrict__ b2,
    float* __restrict__ sum2, float* __restrict__ sq2)
{
    __shared__ alignas(16) unsigned short X1h[128 * 64];
    const int t = threadIdx.x;
    const int pos = t & 127;
    const int half = __builtin_amdgcn_readfirstlane(t >> 7);
    const int p = blockIdx.x * 128 + pos;

    float x = X0[p], y = X0[PTOT + p], z = X0[2 * PTOT + p];
    const int sw = (pos & 7) << 4;
    #pragma unroll
    for (int o2 = 0; o2 < 16; ++o2) {
        int oo = half * 32 + o2 * 2;
        float v0 = b1[oo];
        v0 = fmaf(w1[oo * 3 + 2], z, v0);
        v0 = fmaf(w1[oo * 3 + 1], y, v0);
        v0 = fmaf(w1[oo * 3 + 0], x, v0);
        v0 = fmaxf(fmaf(v0, sc1[oo], sh1[oo]), 0.f);
        float v1 = b1[oo + 1];
        v1 = fmaf(w1[oo * 3 + 5], z, v1);
        v1 = fmaf(w1[oo * 3 + 4], y, v1);
        v1 = fmaf(w1[oo * 3 + 3], x, v1);
        v1 = fmaxf(fmaf(v1, sc1[oo + 1], sh1[oo + 1]), 0.f);
        unsigned short h0 = f2bf(v0), h1 = f2bf(v1);
        int boff = pos * 128 + ((oo * 2) ^ sw);
        *(unsigned*)((char*)X1h + boff) = (unsigned)h0 | ((unsigned)h1 << 16);
    }
    __syncthreads();

    const int wv2 = __builtin_amdgcn_readfirstlane(t >> 6);
    const int lcol = t & 15;
    const int lk = (t & 63) >> 4;

    bf16x8 ah[2];
    #pragma unroll
    for (int kh = 0; kh < 2; ++kh) {
        int idx = (wv2 * 16 + lcol) * 64 + kh * 32 + lk * 8;
        ah[kh] = *(const bf16x8*)(w2h + idx);
    }
    f32x4 b2v = *(const f32x4*)&b2[wv2 * 16 + lk * 4];

    float ssm[2][4] = {{0}}, ssq[2][4] = {{0}};
    #pragma unroll
    for (int nt = 0; nt < 8; ++nt) {
        const int g = nt >> 2;
        int prow = nt * 16 + lcol;
        int rb = prow * 128;
        int psw = (prow & 7) << 4;
        bf16x8 bh[2];
        #pragma unroll
        for (int kh = 0; kh < 2; ++kh) {
            int off = rb + ((kh * 64 + lk * 16) ^ psw);
            bh[kh] = *(const bf16x8*)((const char*)X1h + off);
        }
        f32x4 acc = {0.f, 0.f, 0.f, 0.f};
        MFMA_HI2(acc, ah[0], bh[0], ah[1], bh[1])
        #pragma unroll
        for (int r = 0; r < 4; ++r) {
            float v = acc[r] + b2v[r];
            ssm[g][r] += v;
            ssq[g][r] = fmaf(v, v, ssq[g][r]);
        }
    }
    #pragma unroll
    for (int g = 0; g < 2; ++g) {
        #pragma unroll
        for (int r = 0; r < 4; ++r) {
            float s = ssm[g][r];
            s += DPPF(s, 0xB1);  s += DPPF(s, 0x4E);
            s += DPPF(s, 0x141); s += DPPF(s, 0x140);
            float q = ssq[g][r];
            q += DPPF(q, 0xB1);  q += DPPF(q, 0x4E);
            q += DPPF(q, 0x141); q += DPPF(q, 0x140);
            if (lcol == 0) {
                int o = wv2 * 16 + lk * 4 + r;
                size_t gw = (size_t)(blockIdx.x * 2 + g);
                sum2[(size_t)o * NWAVE + gw] = s;
                sq2[(size_t)o * NWAVE + gw] = q;
            }
        }
    }
}

// ---------------------------------------------------------------------------
// BN finalize (unchanged).
// ---------------------------------------------------------------------------
__global__ __launch_bounds__(256) void bn_finalize_kernel(
    const float* __restrict__ sumb, const float* __restrict__ sqb,
    const float* __restrict__ g, const float* __restrict__ be,
    float* __restrict__ sc, float* __restrict__ sh)
{
    int o = blockIdx.x, t = threadIdx.x;
    double s = 0, q = 0;
    for (int i = t; i < NWAVE; i += 256) {
        s += (double)sumb[(size_t)o * NWAVE + i];
        q += (double)sqb[(size_t)o * NWAVE + i];
    }
    #pragma unroll
    for (int m = 32; m > 0; m >>= 1) {
        s += __shfl_xor(s, m, 64);
        q += __shfl_xor(q, m, 64);
    }
    __shared__ double rs[4], rq[4];
    if ((t & 63) == 0) { rs[t >> 6] = s; rq[t >> 6] = q; }
    __syncthreads();
    if (t == 0) {
        s = rs[0] + rs[1] + rs[2] + rs[3];
        q = rq[0] + rq[1] + rq[2] + rq[3];
        double mean = s / (double)PTOT;
        double var = q / (double)PTOT - mean * mean;
        double scale = (double)g[o] / sqrt(var + 1e-5);
        sc[o] = (float)scale;
        sh[o] = (float)((double)be[o] - mean * scale);
    }
}

// ---------------------------------------------------------------------------
// Pass B: conv1 vector -> X1 bf16 LDS -> conv2 MFMA (identical sequence to
// Pass A) -> BN2+ReLU -> X2 bf16 LDS -> conv3 MFMA -> per-(bk,o) max/min +
// sum/sq from fragments. LDS 32 KB -> ~4 blocks/CU.
// ---------------------------------------------------------------------------
__global__ __launch_bounds__(256) void conv123_kernel(
    const float* __restrict__ X0,
    const float* __restrict__ w1, const float* __restrict__ b1,
    const float* __restrict__ sc1, const float* __restrict__ sh1,
    const unsigned short* __restrict__ w2h, const float* __restrict__ b2,
    const float* __restrict__ sc2, const float* __restrict__ sh2,
    const unsigned short* __restrict__ w3h, const float* __restrict__ b3,
    float* __restrict__ y3max, float* __restrict__ y3min,
    float* __restrict__ sum3, float* __restrict__ sq3)
{
    __shared__ alignas(16) unsigned short X1h[128 * 64];
    __shared__ alignas(16) unsigned short X2h[128 * 64];
    __shared__ alignas(16) float b3L[128];

    const int t = threadIdx.x;
    const int pos = t & 127;
    const int half = __builtin_amdgcn_readfirstlane(t >> 7);
    const int p = blockIdx.x * 128 + pos;
    if (t < 128) b3L[t] = b3[t];

    float x = X0[p], y = X0[PTOT + p], z = X0[2 * PTOT + p];
    const int sw = (pos & 7) << 4;
    #pragma unroll
    for (int o2 = 0; o2 < 16; ++o2) {
        int oo = half * 32 + o2 * 2;
        float v0 = b1[oo];
        v0 = fmaf(w1[oo * 3 + 2], z, v0);
        v0 = fmaf(w1[oo * 3 + 1], y, v0);
        v0 = fmaf(w1[oo * 3 + 0], x, v0);
        v0 = fmaxf(fmaf(v0, sc1[oo], sh1[oo]), 0.f);
        float v1 = b1[oo + 1];
        v1 = fmaf(w1[oo * 3 + 5], z, v1);
        v1 = fmaf(w1[oo * 3 + 4], y, v1);
        v1 = fmaf(w1[oo * 3 + 3], x, v1);
        v1 = fmaxf(fmaf(v1, sc1[oo + 1], sh1[oo + 1]), 0.f);
        unsigned short h0 = f2bf(v0), h1 = f2bf(v1);
        int boff = pos * 128 + ((oo * 2) ^ sw);
        *(unsigned*)((char*)X1h + boff) = (unsigned)h0 | ((unsigned)h1 << 16);
    }
    __syncthreads();

    const int wv2 = __builtin_amdgcn_readfirstlane(t >> 6);
    const int lcol = t & 15;
    const int lk = (t & 63) >> 4;

    // conv2 via MFMA (identical math to Pass A) -> BN2+ReLU -> X2
    {
        bf16x8 ah[2];
        #pragma unroll
        for (int kh = 0; kh < 2; ++kh) {
            int idx = (wv2 * 16 + lcol) * 64 + kh * 32 + lk * 8;
            ah[kh] = *(const bf16x8*)(w2h + idx);
        }
        f32x4 b2v = *(const f32x4*)&b2[wv2 * 16 + lk * 4];
        f32x4 sc2v = *(const f32x4*)&sc2[wv2 * 16 + lk * 4];
        f32x4 sh2v = *(const f32x4*)&sh2[wv2 * 16 + lk * 4];
        const int ch0 = wv2 * 16 + lk * 4;

        #pragma unroll
        for (int nt = 0; nt < 8; ++nt) {
            int prow = nt * 16 + lcol;
            int rb = prow * 128;
            int psw = (prow & 7) << 4;
            bf16x8 bh[2];
            #pragma unroll
            for (int kh = 0; kh < 2; ++kh) {
                int off = rb + ((kh * 64 + lk * 16) ^ psw);
                bh[kh] = *(const bf16x8*)((const char*)X1h + off);
            }
            f32x4 acc = {0.f, 0.f, 0.f, 0.f};
            MFMA_HI2(acc, ah[0], bh[0], ah[1], bh[1])
            unsigned short hh[4];
            #pragma unroll
            for (int r = 0; r < 4; ++r) {
                float v = acc[r] + b2v[r];
                float x2 = fmaxf(fmaf(v, sc2v[r], sh2v[r]), 0.f);
                hh[r] = f2bf(x2);
            }
            int b0 = prow * 128 + ((ch0 * 2) ^ psw);
            *(unsigned*)((char*)X2h + b0)     = (unsigned)hh[0] | ((unsigned)hh[1] << 16);
            *(unsigned*)((char*)X2h + b0 + 4) = (unsigned)hh[2] | ((unsigned)hh[3] << 16);
        }
    }
    __syncthreads();

    // conv3 via MFMA (2 m-tiles/wave over 128 channels)
    bf16x8 ah3[2][2];
    f32x4 bias[2];
    #pragma unroll
    for (int mt = 0; mt < 2; ++mt) {
        #pragma unroll
        for (int kh = 0; kh < 2; ++kh) {
            int m = (wv2 * 2 + mt) * 16 + lcol;
            int idx = m * 64 + kh * 32 + lk * 8;
            ah3[mt][kh] = *(const bf16x8*)(w3h + idx);
        }
        bias[mt] = *(const f32x4*)&b3L[(wv2 * 2 + mt) * 16 + lk * 4];
    }

    float smx[2][2][4], smn[2][2][4], ssm[2][2][4], ssq[2][2][4];
    #pragma unroll
    for (int g = 0; g < 2; ++g)
        #pragma unroll
        for (int mt = 0; mt < 2; ++mt)
            #pragma unroll
            for (int r = 0; r < 4; ++r) {
                smx[g][mt][r] = -1e30f; smn[g][mt][r] = 1e30f;
                ssm[g][mt][r] = 0.f;    ssq[g][mt][r] = 0.f;
            }

    #pragma unroll
    for (int nt = 0; nt < 8; ++nt) {
        const int g = nt >> 2;
        int prow = nt * 16 + lcol;
        int rb = prow * 128;
        int psw = (prow & 7) << 4;
        bf16x8 bh[2];
        #pragma unroll
        for (int kh = 0; kh < 2; ++kh) {
            int off = rb + ((kh * 64 + lk * 16) ^ psw);
            bh[kh] = *(const bf16x8*)((const char*)X2h + off);
        }
        #pragma unroll
        for (int mt = 0; mt < 2; ++mt) {
            f32x4 acc = {0.f, 0.f, 0.f, 0.f};
            MFMA_HI2(acc, ah3[mt][0], bh[0], ah3[mt][1], bh[1])
            #pragma unroll
            for (int r = 0; r < 4; ++r) {
                float v = acc[r] + bias[mt][r];
                smx[g][mt][r] = fmaxf(smx[g][mt][r], v);
                smn[g][mt][r] = fminf(smn[g][mt][r], v);
                ssm[g][mt][r] += v;
                ssq[g][mt][r] = fmaf(v, v, ssq[g][mt][r]);
            }
        }
    }

    #pragma unroll
    for (int g = 0; g < 2; ++g) {
        #pragma unroll
        for (int mt = 0; mt < 2; ++mt) {
            #pragma unroll
            for (int r = 0; r < 4; ++r) {
                float a = smx[g][mt][r];
                a = fmaxf(a, DPPF(a, 0xB1));  a = fmaxf(a, DPPF(a, 0x4E));
                a = fmaxf(a, DPPF(a, 0x141)); a = fmaxf(a, DPPF(a, 0x140));
                float c = smn[g][mt][r];
                c = fminf(c, DPPF(c, 0xB1));  c = fminf(c, DPPF(c, 0x4E));
                c = fminf(c, DPPF(c, 0x141)); c = fminf(c, DPPF(c, 0x140));
                float s = ssm[g][mt][r];
                s += DPPF(s, 0xB1);  s += DPPF(s, 0x4E);
                s += DPPF(s, 0x141); s += DPPF(s, 0x140);
                float q = ssq[g][mt][r];
                q += DPPF(q, 0xB1);  q += DPPF(q, 0x4E);
                q += DPPF(q, 0x141); q += DPPF(q, 0x140);
                if (lcol == 0) {
                    int o = (wv2 * 2 + mt) * 16 + lk * 4 + r;
                    size_t gw = (size_t)(blockIdx.x * 2 + g);
                    y3max[gw * 128 + o] = a;
                    y3min[gw * 128 + o] = c;
                    sum3[(size_t)o * NWAVE + gw] = s;
                    sq3[(size_t)o * NWAVE + gw] = q;
                }
            }
        }
    }
}

// ---------------------------------------------------------------------------
// Final feats (unchanged).
// ---------------------------------------------------------------------------
__global__ __launch_bounds__(256) void feats_kernel(
    const float* __restrict__ y3max, const float* __restrict__ y3min,
    const float* __restrict__ sc3, const float* __restrict__ sh3,
    float* __restrict__ feats)
{
    __shared__ float tile[64][129];
    int blk = blockIdx.x;
    int b = blk >> 4, kt = blk & 15;
    int t = threadIdx.x;
    size_t bk0 = (size_t)(b * KREG + kt * 64);
    #pragma unroll
    for (int i = 0; i < 32; ++i) {
        int idx = i * 256 + t;
        int o = idx & 127, kk = idx >> 7;
        float a = sc3[o];
        float v = (a >= 0.f) ? y3max[(bk0 + kk) * 128 + o]
                             : y3min[(bk0 + kk) * 128 + o];
        tile[kk][o] = fmaxf(fmaf(v, a, sh3[o]), 0.0f);
    }
    __syncthreads();
    #pragma unroll
    for (int i = 0; i < 32; ++i) {
        int idx = i * 256 + t;
        int kk = idx & 63, o = idx >> 6;
        feats[(size_t)b * 128 * KREG + (size_t)o * KREG + kt * 64 + kk] = tile[kk][o];
    }
}

// ---------------------------------------------------------------------------
extern "C" void kernel_launch(void* const* d_in, const int* in_sizes, int n_in,
                              void* d_out, int out_size, void* d_ws, size_t ws_size,
                              hipStream_t stream)
{
    const float* pc  = (const float*)d_in[0];
    const float* w1  = (const float*)d_in[1];
    const float* b1  = (const float*)d_in[2];
    const float* g1  = (const float*)d_in[3];
    const float* be1 = (const float*)d_in[4];
    const float* w2  = (const float*)d_in[5];
    const float* b2  = (const float*)d_in[6];
    const float* g2  = (const float*)d_in[7];
    const float* be2 = (const float*)d_in[8];
    const float* w3  = (const float*)d_in[9];
    const float* b3  = (const float*)d_in[10];
    const float* g3  = (const float*)d_in[11];
    const float* be3 = (const float*)d_in[12];

    float* outC  = (float*)d_out;                      // (16,3,1024)
    float* feats = (float*)d_out + NB * 3 * KREG;      // (16,128,1024)

    const size_t MB = 1024 * 1024;
    char* ws = (char*)d_ws;
    int*   gidx  = (int*)ws;                           // 4 MB
    float* X0    = (float*)(ws + 4 * MB);              // 12 MB (3 x P)
    float* mpart = (float*)(ws + 16 * MB);             // 9216 B
    float* sc1   = (float*)(ws + 16 * MB + 16 * 1024);
    float* sh1   = (float*)(ws + 16 * MB + 17 * 1024);
    float* sc2   = (float*)(ws + 16 * MB + 18 * 1024);
    float* sh2   = (float*)(ws + 16 * MB + 19 * 1024);
    float* sc3   = (float*)(ws + 16 * MB + 20 * 1024);
    float* sh3   = (float*)(ws + 16 * MB + 21 * 1024);
    unsigned short* w2h = (unsigned short*)(ws + 16 * MB + 32 * 1024);  // 8 KB
    unsigned short* w3h = (unsigned short*)(ws + 16 * MB + 64 * 1024);  // 16 KB
    float* sum2  = (float*)(ws + 17 * MB);             // 4 MB
    float* sq2   = (float*)(ws + 21 * MB);             // 4 MB
    float* sum3  = (float*)(ws + 25 * MB);             // 8 MB
    float* sq3   = (float*)(ws + 33 * MB);             // 8 MB
    float* y3max = (float*)(ws + 41 * MB);             // 8 MB
    float* y3min = (float*)(ws + 49 * MB);             // 8 MB

    fps_kernel<<<NB, 256, 0, stream>>>(pc, outC);
    ballquery_kernel<<<(NB * KREG) / 16, 256, 0, stream>>>(pc, outC, gidx);
    gather_kernel<<<GATH_BLOCKS, 256, 0, stream>>>(pc, outC, gidx, X0, mpart);
    bn1_finalize<<<1, 64, 0, stream>>>(mpart, w1, b1, g1, be1, sc1, sh1);
    prep_kernel<<<32, 256, 0, stream>>>(w2, w3, w2h, w3h);
    conv12_stats_kernel<<<PTOT / 128, 256, 0, stream>>>(
        X0, w1, b1, sc1, sh1, w2h, b2, sum2, sq2);
    bn_finalize_kernel<<<64, 256, 0, stream>>>(sum2, sq2, g2, be2, sc2, sh2);
    conv123_kernel<<<PTOT / 128, 256, 0, stream>>>(
        X0, w1, b1, sc1, sh1, w2h, b2, sc2, sh2, w3h, b3,
        y3max, y3min, sum3, sq3);
    bn_finalize_kernel<<<128, 256, 0, stream>>>(sum3, sq3, g3, be3, sc3, sh3);
    feats_kernel<<<NB * (KREG / 64), 256, 0, stream>>>(y3max, y3min, sc3, sh3, feats);
}